// Round 14
// baseline (159.652 us; speedup 1.0000x reference)
//
#include <hip/hip_runtime.h>

// Problem: B=2, S=4096, E=512, H=8, D=64, window 512->513 (HALF=256)
#define S_LEN  4096
#define NH     8
#define DH     64
#define EMB    512
#define HDIM   512
#define HALF_W 256
#define BATCH  2
#define M_ROWS (BATCH * S_LEN)  // 8192

typedef __attribute__((ext_vector_type(8))) short bf16x8;
typedef __attribute__((ext_vector_type(4))) float f32x4;

// ---------- bf16 helpers ----------
__device__ __forceinline__ float b2f(unsigned short u) {
    union { unsigned int i; float f; } v; v.i = ((unsigned int)u) << 16; return v.f;
}
__device__ __forceinline__ unsigned short f2b(float f) {
    unsigned int x = __float_as_uint(f);
    unsigned int r = (x + 0x7fffu + ((x >> 16) & 1u)) >> 16;   // RNE
    return (unsigned short)r;
}
__device__ __forceinline__ void unpack2(unsigned int u, float* d) {
    d[0] = b2f((unsigned short)(u & 0xffffu));
    d[1] = b2f((unsigned short)(u >> 16));
}
union FragU { uint4 u; bf16x8 f; };
__device__ __forceinline__ bf16x8 ldfrag(const unsigned short* p) {
    FragU x; x.u = *(const uint4*)p; return x.f;
}

// ---------- async global->LDS, 16B per lane (m97 pattern) ----------
__device__ __forceinline__ void async16(const unsigned short* g, unsigned short* l) {
    __builtin_amdgcn_global_load_lds(
        (__attribute__((address_space(1))) void*)const_cast<unsigned short*>(g),
        (__attribute__((address_space(3))) void*)l, 16, 0, 0);
}

// ---------- inline dtype detect (per-block; deterministic, L2-hot 4KB scan) ----------
__device__ __forceinline__ int detect_flag(const unsigned short* __restrict__ xq) {
    __shared__ int s_flag;
    if (threadIdx.x == 0) s_flag = 0;
    __syncthreads();
    uint4 u = *(const uint4*)(xq + threadIdx.x * 8);
    const unsigned short* us = (const unsigned short*)&u;
    int bad = 0;
#pragma unroll
    for (int i = 0; i < 8; ++i) {
        float v = b2f(us[i]);
        if (!(fabsf(v) < 1.0e6f)) bad = 1;
    }
    if (__any(bad) && (threadIdx.x & 63) == 0) atomicOr(&s_flag, 1);
    __syncthreads();
    return s_flag;   // 1 = fp32 inputs, 0 = bf16 inputs
}

// ---------- fused prep: weight transpose->Wt[n][k] bf16  +  input fp32->bf16 convert ----------
__global__ __launch_bounds__(256) void prep(
    const void* __restrict__ xq, const void* __restrict__ xkv,
    const void* __restrict__ w0, const void* __restrict__ w1,
    const void* __restrict__ w2, const void* __restrict__ w3,
    unsigned short* __restrict__ Wt, unsigned short* __restrict__ Xc)
{
    const int flag = detect_flag((const unsigned short*)xq);
    const int blk = blockIdx.x;
    if (blk < 1024) {
        __shared__ float t[32][33];
        const int z = blk >> 8, idx = blk & 255;
        const void* src = (z == 0) ? w0 : (z == 1) ? w1 : (z == 2) ? w2 : w3;
        unsigned short* dst = Wt + (size_t)z * EMB * EMB;
        const int n0 = (idx & 15) << 5, k0 = (idx >> 4) << 5;
        const int kk = threadIdx.x >> 3;
        const int n4 = (threadIdx.x & 7) << 2;
        if (flag) {
            float4 v = *(const float4*)((const float*)src + (size_t)(k0 + kk) * EMB + n0 + n4);
            t[kk][n4] = v.x; t[kk][n4 + 1] = v.y; t[kk][n4 + 2] = v.z; t[kk][n4 + 3] = v.w;
        } else {
            uint2 u = *(const uint2*)((const unsigned short*)src + (size_t)(k0 + kk) * EMB + n0 + n4);
            unpack2(u.x, &t[kk][n4]); unpack2(u.y, &t[kk][n4 + 2]);
        }
        __syncthreads();
        const int nn = threadIdx.x >> 3;
        const int ks = (threadIdx.x & 7) << 2;
        uint2 pk;
        pk.x = (unsigned int)f2b(t[ks + 0][nn]) | ((unsigned int)f2b(t[ks + 1][nn]) << 16);
        pk.y = (unsigned int)f2b(t[ks + 2][nn]) | ((unsigned int)f2b(t[ks + 3][nn]) << 16);
        *(uint2*)(dst + (size_t)(n0 + nn) * EMB + k0 + ks) = pk;
    } else {
        if (!flag) return;
        const int idx = blk - 1024;
        const int z = idx >> 11;                 // 0 = xq, 1 = xkv
        const float* src = (const float*)(z ? xkv : xq);
        unsigned short* dst = Xc + (size_t)z * M_ROWS * EMB;
        const size_t base = ((size_t)(idx & 2047) * 256 + threadIdx.x) * 8;
        float4 a = *(const float4*)(src + base);
        float4 b = *(const float4*)(src + base + 4);
        uint4 pk;
        pk.x = (unsigned int)f2b(a.x) | ((unsigned int)f2b(a.y) << 16);
        pk.y = (unsigned int)f2b(a.z) | ((unsigned int)f2b(a.w) << 16);
        pk.z = (unsigned int)f2b(b.x) | ((unsigned int)f2b(b.y) << 16);
        pk.w = (unsigned int)f2b(b.z) | ((unsigned int)f2b(b.w) << 16);
        *(uint4*)(dst + base) = pk;
    }
}

// ---------- MFMA GEMM core v8: 128x128, BK=64, RING-4, ONE barrier per K-step ----------
// v7 (3-buf, 2 barriers/step) was neutral vs v6 -> prefetch depth isn't the wall;
// the barrier PAIR is. Ring-4 + stage-ahead-2 needs only one barrier per step:
//  order: stage(ks+2) -> vmcnt(16) -> s_barrier -> compute(c0).
//  Publication: each wave's vmcnt(16) (outstanding {ks,ks+1,ks+2}=24 -> retires
//   chunk-ks) precedes its barrier arrival => when any wave passes barrier(ks),
//   ALL waves' chunk-ks loads landed.
//  WAR: iter ks stages over the buffer read at iter ks-2 (ring-4 reuse period);
//   the stager passed barrier(ks-1), whose release implies all waves finished
//   compute(ks-2). (Ring-3 would reuse the ks-1 buffer -> race; 4 is minimal.)
// Tail: vmcnt 16 -> 8 -> 0. LDS 128 KB -> 1 block/CU (same as v7's 96 KB).
template<bool SWAP>
__device__ __forceinline__ void mgemm_core8(
    const unsigned short* __restrict__ A, const unsigned short* __restrict__ Bt,
    int m0, f32x4 (*acc)[4],
    unsigned short (*A_lds)[128][64], unsigned short (*B_lds)[128][64])
{
    const int tid  = threadIdx.x;
    const int lane = tid & 63;
    const int w    = tid >> 6;
    const int wm   = (w >> 1) << 6;
    const int wn   = (w & 1) << 6;
    const int qcol = lane & 15;
    const int quad = lane >> 4;

    const int srow = tid >> 3;   // 0..31
    const int sp   = tid & 7;

    auto stage = [&](int bf, int k0) {
#pragma unroll
        for (int i = 0; i < 4; ++i) {
            const int row  = (i << 5) + srow;            // 0..127
            const int gcol = ((sp ^ (row & 7)) << 3);
            async16(A + (size_t)(m0 + row) * EMB + k0 + gcol, &A_lds[bf][row][sp << 3]);
            async16(Bt + (size_t)row * EMB + k0 + gcol, &B_lds[bf][row][sp << 3]);
        }
    };

    stage(0, 0);
    stage(1, 64);            // prologue: 16 outstanding

    int c0 = 0, c1 = 1, c2 = 2, c3 = 3;
    for (int ks = 0; ks < 8; ++ks) {
        if (ks < 6) {
            stage(c2, (ks + 2) << 6);                         // 24 outstanding
            asm volatile("s_waitcnt vmcnt(16)" ::: "memory"); // retire step-ks's 8
        } else if (ks == 6) {
            asm volatile("s_waitcnt vmcnt(8)" ::: "memory");
        } else {
            asm volatile("s_waitcnt vmcnt(0)" ::: "memory");
        }
        __builtin_amdgcn_sched_barrier(0);
        __builtin_amdgcn_s_barrier();          // single barrier: publish + WAR guard

#pragma unroll
        for (int kh = 0; kh < 2; ++kh) {
            bf16x8 af[4], bf[4];
#pragma unroll
            for (int i = 0; i < 4; ++i) {
                const int arow = wm + (i << 4) + qcol;
                af[i] = ldfrag(&A_lds[c0][arow][((((kh << 2) + quad) ^ (arow & 7)) << 3)]);
                const int brow = wn + (i << 4) + qcol;
                bf[i] = ldfrag(&B_lds[c0][brow][((((kh << 2) + quad) ^ (brow & 7)) << 3)]);
            }
#pragma unroll
            for (int i = 0; i < 4; ++i)
#pragma unroll
                for (int j = 0; j < 4; ++j) {
                    if (SWAP)
                        acc[i][j] = __builtin_amdgcn_mfma_f32_16x16x32_bf16(bf[j], af[i], acc[i][j], 0, 0, 0);
                    else
                        acc[i][j] = __builtin_amdgcn_mfma_f32_16x16x32_bf16(af[i], bf[j], acc[i][j], 0, 0, 0);
                }
        }
        const int t = c0; c0 = c1; c1 = c2; c2 = c3; c3 = t;   // rotate ring-4
    }
}

// fused QKV: 768 blocks; XCD-grouped
__global__ __launch_bounds__(256) void gemm_qkv(
    const void* __restrict__ xq, const void* __restrict__ xkv,
    const unsigned short* __restrict__ Xc, const unsigned short* __restrict__ Wt,
    unsigned short* __restrict__ Qb, unsigned short* __restrict__ Kb,
    unsigned short* __restrict__ Vtb)
{
    const int flag = detect_flag((const unsigned short*)xq);
    __shared__ __align__(16) unsigned short A_lds[4][128][64];
    __shared__ __align__(16) unsigned short B_lds[4][128][64];
    const int blk = blockIdx.x;
    const int xcd = blk & 7, idx = blk >> 3;
    const int mi = idx / 12, ni = idx - mi * 12;
    const int m0 = ((xcd << 3) + mi) << 7;
    const int n0 = ni << 7;

    const unsigned short* A;
    if (flag) A = Xc + (n0 < 512 ? (size_t)0 : (size_t)M_ROWS * EMB);
    else      A = (const unsigned short*)(n0 < 512 ? xq : xkv);
    const unsigned short* Bt = Wt + (size_t)n0 * EMB;

    f32x4 acc[4][4];
#pragma unroll
    for (int i = 0; i < 4; ++i)
#pragma unroll
        for (int j = 0; j < 4; ++j) acc[i][j] = (f32x4){0.f, 0.f, 0.f, 0.f};

    const int lane = threadIdx.x & 63, w = threadIdx.x >> 6;
    const int wm = (w >> 1) << 6, wn = (w & 1) << 6;
    const int qcol = lane & 15, quad = lane >> 4;
    const int mode = n0 >> 9;   // 0=Q, 1=K, 2=V (512%128==0: tile stays in one mode)

    if (mode == 2) {
        mgemm_core8<false>(A, Bt, m0, acc, A_lds, B_lds);
#pragma unroll
        for (int ms = 0; ms < 4; ++ms)
#pragma unroll
            for (int ns = 0; ns < 4; ++ns) {
                const int mbase = m0 + wm + (ms << 4) + (quad << 2);
                const int n = n0 + wn + (ns << 4) + qcol;
                const int hd = n - 1024;
                const int hh = hd >> 6, d = hd & 63;
                const int bb = mbase >> 12, s = mbase & (S_LEN - 1);
                uint2 pk;
                pk.x = (unsigned int)f2b(acc[ms][ns][0]) | ((unsigned int)f2b(acc[ms][ns][1]) << 16);
                pk.y = (unsigned int)f2b(acc[ms][ns][2]) | ((unsigned int)f2b(acc[ms][ns][3]) << 16);
                *(uint2*)(Vtb + ((size_t)((bb * NH + hh) * DH + d)) * S_LEN + s) = pk;
            }
    } else {
        mgemm_core8<true>(A, Bt, m0, acc, A_lds, B_lds);
#pragma unroll
        for (int i = 0; i < 4; ++i)
#pragma unroll
            for (int j = 0; j < 4; ++j) {
                const int m  = m0 + wm + (i << 4) + qcol;
                const int nb = n0 + wn + (j << 4) + (quad << 2);
                uint2 pk;
                pk.x = (unsigned int)f2b(acc[i][j][0]) | ((unsigned int)f2b(acc[i][j][1]) << 16);
                pk.y = (unsigned int)f2b(acc[i][j][2]) | ((unsigned int)f2b(acc[i][j][3]) << 16);
                if (mode == 0) *(uint2*)(Qb + (size_t)m * HDIM + nb) = pk;
                else           *(uint2*)(Kb + (size_t)m * HDIM + (nb - 512)) = pk;
            }
    }
}

// output projection: 256 blocks; XCD-grouped
__global__ __launch_bounds__(256) void gemm_out(
    const void* __restrict__ xq,
    const unsigned short* __restrict__ A, const unsigned short* __restrict__ Bt,
    void* __restrict__ C)
{
    const int flag = detect_flag((const unsigned short*)xq);
    __shared__ __align__(16) unsigned short A_lds[4][128][64];
    __shared__ __align__(16) unsigned short B_lds[4][128][64];
    const int blk = blockIdx.x;
    const int xcd = blk & 7, idx = blk >> 3;
    const int mi = idx >> 2, ni = idx & 3;
    const int m0 = ((xcd << 3) + mi) << 7;
    const int n0 = ni << 7;

    f32x4 acc[4][4];
#pragma unroll
    for (int i = 0; i < 4; ++i)
#pragma unroll
        for (int j = 0; j < 4; ++j) acc[i][j] = (f32x4){0.f, 0.f, 0.f, 0.f};

    mgemm_core8<true>(A, Bt + (size_t)n0 * EMB, m0, acc, A_lds, B_lds);

    const int lane = threadIdx.x & 63, w = threadIdx.x >> 6;
    const int wm = (w >> 1) << 6, wn = (w & 1) << 6;
    const int qcol = lane & 15, quad = lane >> 4;
#pragma unroll
    for (int i = 0; i < 4; ++i)
#pragma unroll
        for (int j = 0; j < 4; ++j) {
            const int m  = m0 + wm + (i << 4) + qcol;
            const int nb = n0 + wn + (j << 4) + (quad << 2);
            if (flag) {
                float4 v = {acc[i][j][0], acc[i][j][1], acc[i][j][2], acc[i][j][3]};
                *(float4*)((float*)C + (size_t)m * HDIM + nb) = v;
            } else {
                uint2 pk;
                pk.x = (unsigned int)f2b(acc[i][j][0]) | ((unsigned int)f2b(acc[i][j][1]) << 16);
                pk.y = (unsigned int)f2b(acc[i][j][2]) | ((unsigned int)f2b(acc[i][j][3]) << 16);
                *(uint2*)((unsigned short*)C + (size_t)m * HDIM + nb) = pk;
            }
        }
}

// ---------- MFMA flash attention v6 (unchanged; part of measured 158.26 config) ----------
// NOTE: 1-barrier ring-4 NOT applied here: K/V/P LDS would grow 50->82 KB,
// halving occupancy (16->8 waves/CU) — the R10->R13 lever — for 10 fewer barriers.
__global__ __launch_bounds__(512) void attn_mfma(
    const unsigned short* __restrict__ Q,
    const unsigned short* __restrict__ Kg,
    const unsigned short* __restrict__ Vt,
    unsigned short* __restrict__ O)
{
    __shared__ __align__(16) unsigned short K_lds[2][64][64];    // [buf][key][d]
    __shared__ __align__(16) unsigned short V_lds[2][64][64];    // [buf][d][key]
    __shared__ __align__(16) unsigned short P_lds[8][16][72];    // per-wave [q][key]

    const int tid  = threadIdx.x;
    const int lane = tid & 63;
    const int w    = tid >> 6;                      // 0..7
    const int blk  = blockIdx.x;
    const int bh   = blk >> 5;
    const int r5   = blk & 31;
    const int tile = ((r5 & 7) << 2) | (r5 >> 3);   // xcd = blk%8 owns 4 contiguous tiles
    const int h    = bh & (NH - 1);
    const int b    = bh >> 3;
    const int t0   = tile << 7;
    const int tq0  = t0 + (w << 4);                 // wave's 16 queries

    const int qcol = lane & 15;
    const int quad = lane >> 4;
    const float slope = 1.0f / (float)(2 << h);     // 2^-(h+1)

    const unsigned short* qrow =
        Q + (size_t)(b * S_LEN + tq0 + qcol) * HDIM + h * DH;
    const bf16x8 qf0 = ldfrag(qrow + quad * 8);
    const bf16x8 qf1 = ldfrag(qrow + 32 + quad * 8);

    f32x4 Oacc[4];
#pragma unroll
    for (int i = 0; i < 4; ++i) Oacc[i] = (f32x4){0.f, 0.f, 0.f, 0.f};
    float lsum = 0.f;

    const int srow = tid >> 3;   // 0..63
    const int sp   = tid & 7;

    // stage one 64-key chunk (2 global_load_lds per thread: 1 K-row seg + 1 V-row seg)
    auto stage = [&](int bf, int c) {
        const int j0 = t0 - HALF_W + (c << 6);
        const int gseg = (sp ^ (srow & 7)) << 3;
        const int jc = min(max(j0 + srow, 0), S_LEN - 1);
        async16(Kg + (size_t)(b * S_LEN + jc) * HDIM + h * DH + gseg,
                &K_lds[bf][srow][sp << 3]);
        const int js = min(max(j0 + gseg, 0), S_LEN - 8);
        async16(Vt + ((size_t)((b * NH + h) * DH + srow)) * S_LEN + js,
                &V_lds[bf][srow][sp << 3]);
    };

    stage(0, 0);   // prologue

    for (int c = 0; c < 10; ++c) {
        const int cur = c & 1;
        if (c < 9) {
            stage(cur ^ 1, c + 1);                       // prefetch next chunk
            asm volatile("s_waitcnt vmcnt(2)" ::: "memory");  // chunk c's 2 loads done
        } else {
            asm volatile("s_waitcnt vmcnt(0)" ::: "memory");
        }
        __builtin_amdgcn_sched_barrier(0);
        __builtin_amdgcn_s_barrier();                    // chunk c LDS visible to all waves

        const int j0 = t0 - HALF_W + (c << 6);

        // S^T + mask/exp -> P_lds
#pragma unroll
        for (int ks = 0; ks < 4; ++ks) {
            const int krow = (ks << 4) + qcol;
            const bf16x8 kf0 = ldfrag(&K_lds[cur][krow][(quad ^ (krow & 7)) << 3]);
            const bf16x8 kf1 = ldfrag(&K_lds[cur][krow][((4 + quad) ^ (krow & 7)) << 3]);
            f32x4 z = (f32x4){0.f, 0.f, 0.f, 0.f};
            __builtin_amdgcn_s_setprio(1);
            z = __builtin_amdgcn_mfma_f32_16x16x32_bf16(kf0, qf0, z, 0, 0, 0);
            z = __builtin_amdgcn_mfma_f32_16x16x32_bf16(kf1, qf1, z, 0, 0, 0);
            __builtin_amdgcn_s_setprio(0);
            unsigned short pb[4];
#pragma unroll
            for (int r = 0; r < 4; ++r) {
                const int j  = j0 + (ks << 4) + (quad << 2) + r;
                const int dd = (tq0 + qcol) - j;
                const bool ok = (j >= 0) && (j < S_LEN) && (dd <= HALF_W) && (dd >= -HALF_W);
                const float s = z[r] * 0.125f - slope * fabsf((float)dd);
                const float p = ok ? __expf(s - 12.0f) : 0.0f;
                lsum += p;
                pb[r] = f2b(p);
            }
            uint2 pk;
            pk.x = (unsigned int)pb[0] | ((unsigned int)pb[1] << 16);
            pk.y = (unsigned int)pb[2] | ((unsigned int)pb[3] << 16);
            *(uint2*)&P_lds[w][qcol][(ks << 4) + (quad << 2)] = pk;
        }
        // O^T += V^T P^T
        {
            const bf16x8 pf0 = ldfrag(&P_lds[w][qcol][quad * 8]);
            const bf16x8 pf1 = ldfrag(&P_lds[w][qcol][32 + quad * 8]);
#pragma unroll
            for (int ds = 0; ds < 4; ++ds) {
                const int vrow = (ds << 4) + qcol;
                const bf16x8 vf0 = ldfrag(&V_lds[cur][vrow][(quad ^ (vrow & 7)) << 3]);
                const bf16x8 vf1 = ldfrag(&V_lds[cur][vrow][((4 + quad) ^ (vrow & 7)) << 3]);
                __builtin_amdgcn_s_setprio(1);
                Oacc[ds] = __builtin_amdgcn_mfma_f32_16x16x32_bf16(vf0, pf0, Oacc[ds], 0, 0, 0);
                Oacc[ds] = __builtin_amdgcn_mfma_f32_16x16x32_bf16(vf1, pf1, Oacc[ds], 0, 0, 0);
                __builtin_amdgcn_s_setprio(0);
            }
        }
        __builtin_amdgcn_s_barrier();   // all waves done reading buf[cur] before re-stage
    }

    {
        float l = lsum;
        l += __shfl_xor(l, 16, 64);
        l += __shfl_xor(l, 32, 64);
        const float rz = 1.0f / l;
        unsigned short* obase =
            O + (size_t)(b * S_LEN + tq0 + qcol) * HDIM + h * DH;
#pragma unroll
        for (int ds = 0; ds < 4; ++ds) {
            uint2 pk;
            pk.x = (unsigned int)f2b(Oacc[ds][0] * rz) |
                   ((unsigned int)f2b(Oacc[ds][1] * rz) << 16);
            pk.y = (unsigned int)f2b(Oacc[ds][2] * rz) |
                   ((unsigned int)f2b(Oacc[ds][3] * rz) << 16);
            *(uint2*)(obase + (ds << 4) + (quad << 2)) = pk;
        }
    }
}

// ---------- launch: 4 kernels ----------
extern "C" void kernel_launch(void* const* d_in, const int* in_sizes, int n_in,
                              void* d_out, int out_size, void* d_ws, size_t ws_size,
                              hipStream_t stream) {
    const void* xq  = d_in[0];
    const void* xkv = d_in[1];
    const void* wq  = d_in[2];
    const void* wk  = d_in[3];
    const void* wv  = d_in[4];
    const void* wo  = d_in[5];

    // ws: [pad 256B][Q/A 8MB][K 8MB][Vt 8MB][Wt 4x0.5MB]; bf16 input staging in d_out
    unsigned short* Qb  = (unsigned short*)((char*)d_ws + 256);
    unsigned short* Kb  = Qb  + (size_t)M_ROWS * HDIM;
    unsigned short* Vtb = Kb  + (size_t)M_ROWS * HDIM;
    unsigned short* Wt  = Vtb + (size_t)M_ROWS * HDIM;
    unsigned short* Wto = Wt + (size_t)3 * EMB * EMB;
    unsigned short* Xc  = (unsigned short*)d_out;   // dead until gemm_out writes it

    prep<<<1024 + 4096, 256, 0, stream>>>(xq, xkv, wq, wk, wv, wo, Wt, Xc);
    gemm_qkv<<<768, 256, 0, stream>>>(xq, xkv, Xc, Wt, Qb, Kb, Vtb);
    attn_mfma<<<BATCH * NH * (S_LEN / 128), 512, 0, stream>>>(Qb, Kb, Vtb, Qb);
    gemm_out<<<256, 256, 0, stream>>>(xq, Qb, Wto, d_out);
}

// Round 17
// 153.925 us; speedup vs baseline: 1.0372x; 1.0372x over previous
//
#include <hip/hip_runtime.h>

// Problem: B=2, S=4096, E=512, H=8, D=64, window 512->513 (HALF=256)
#define S_LEN  4096
#define NH     8
#define DH     64
#define EMB    512
#define HDIM   512
#define HALF_W 256
#define BATCH  2
#define M_ROWS (BATCH * S_LEN)  // 8192

typedef __attribute__((ext_vector_type(8))) short bf16x8;
typedef __attribute__((ext_vector_type(4))) float f32x4;

// ---------- bf16 helpers ----------
__device__ __forceinline__ float b2f(unsigned short u) {
    union { unsigned int i; float f; } v; v.i = ((unsigned int)u) << 16; return v.f;
}
__device__ __forceinline__ unsigned short f2b(float f) {
    unsigned int x = __float_as_uint(f);
    unsigned int r = (x + 0x7fffu + ((x >> 16) & 1u)) >> 16;   // RNE
    return (unsigned short)r;
}
__device__ __forceinline__ void unpack2(unsigned int u, float* d) {
    d[0] = b2f((unsigned short)(u & 0xffffu));
    d[1] = b2f((unsigned short)(u >> 16));
}
union FragU { uint4 u; bf16x8 f; };
__device__ __forceinline__ bf16x8 ldfrag(const unsigned short* p) {
    FragU x; x.u = *(const uint4*)p; return x.f;
}

// ---------- async global->LDS, 16B per lane (m97 pattern) ----------
__device__ __forceinline__ void async16(const unsigned short* g, unsigned short* l) {
    __builtin_amdgcn_global_load_lds(
        (__attribute__((address_space(1))) void*)const_cast<unsigned short*>(g),
        (__attribute__((address_space(3))) void*)l, 16, 0, 0);
}

// ---------- inline dtype detect (per-block; deterministic, L2-hot 4KB scan) ----------
__device__ __forceinline__ int detect_flag(const unsigned short* __restrict__ xq) {
    __shared__ int s_flag;
    if (threadIdx.x == 0) s_flag = 0;
    __syncthreads();
    uint4 u = *(const uint4*)(xq + threadIdx.x * 8);
    const unsigned short* us = (const unsigned short*)&u;
    int bad = 0;
#pragma unroll
    for (int i = 0; i < 8; ++i) {
        float v = b2f(us[i]);
        if (!(fabsf(v) < 1.0e6f)) bad = 1;
    }
    if (__any(bad) && (threadIdx.x & 63) == 0) atomicOr(&s_flag, 1);
    __syncthreads();
    return s_flag;   // 1 = fp32 inputs, 0 = bf16 inputs
}

// ---------- fused prep: weight transpose->Wt[n][k] bf16  +  input fp32->bf16 convert ----------
__global__ __launch_bounds__(256) void prep(
    const void* __restrict__ xq, const void* __restrict__ xkv,
    const void* __restrict__ w0, const void* __restrict__ w1,
    const void* __restrict__ w2, const void* __restrict__ w3,
    unsigned short* __restrict__ Wt, unsigned short* __restrict__ Xc)
{
    const int flag = detect_flag((const unsigned short*)xq);
    const int blk = blockIdx.x;
    if (blk < 1024) {
        __shared__ float t[32][33];
        const int z = blk >> 8, idx = blk & 255;
        const void* src = (z == 0) ? w0 : (z == 1) ? w1 : (z == 2) ? w2 : w3;
        unsigned short* dst = Wt + (size_t)z * EMB * EMB;
        const int n0 = (idx & 15) << 5, k0 = (idx >> 4) << 5;
        const int kk = threadIdx.x >> 3;
        const int n4 = (threadIdx.x & 7) << 2;
        if (flag) {
            float4 v = *(const float4*)((const float*)src + (size_t)(k0 + kk) * EMB + n0 + n4);
            t[kk][n4] = v.x; t[kk][n4 + 1] = v.y; t[kk][n4 + 2] = v.z; t[kk][n4 + 3] = v.w;
        } else {
            uint2 u = *(const uint2*)((const unsigned short*)src + (size_t)(k0 + kk) * EMB + n0 + n4);
            unpack2(u.x, &t[kk][n4]); unpack2(u.y, &t[kk][n4 + 2]);
        }
        __syncthreads();
        const int nn = threadIdx.x >> 3;
        const int ks = (threadIdx.x & 7) << 2;
        uint2 pk;
        pk.x = (unsigned int)f2b(t[ks + 0][nn]) | ((unsigned int)f2b(t[ks + 1][nn]) << 16);
        pk.y = (unsigned int)f2b(t[ks + 2][nn]) | ((unsigned int)f2b(t[ks + 3][nn]) << 16);
        *(uint2*)(dst + (size_t)(n0 + nn) * EMB + k0 + ks) = pk;
    } else {
        if (!flag) return;
        const int idx = blk - 1024;
        const int z = idx >> 11;                 // 0 = xq, 1 = xkv
        const float* src = (const float*)(z ? xkv : xq);
        unsigned short* dst = Xc + (size_t)z * M_ROWS * EMB;
        const size_t base = ((size_t)(idx & 2047) * 256 + threadIdx.x) * 8;
        float4 a = *(const float4*)(src + base);
        float4 b = *(const float4*)(src + base + 4);
        uint4 pk;
        pk.x = (unsigned int)f2b(a.x) | ((unsigned int)f2b(a.y) << 16);
        pk.y = (unsigned int)f2b(a.z) | ((unsigned int)f2b(a.w) << 16);
        pk.z = (unsigned int)f2b(b.x) | ((unsigned int)f2b(b.y) << 16);
        pk.w = (unsigned int)f2b(b.z) | ((unsigned int)f2b(b.w) << 16);
        *(uint4*)(dst + base) = pk;
    }
}

// ---------- MFMA GEMM core v7 (REVERTED to best-measured 158.26 config): 3-buf ring ----------
template<bool SWAP>
__device__ __forceinline__ void mgemm_core7(
    const unsigned short* __restrict__ A, const unsigned short* __restrict__ Bt,
    int m0, f32x4 (*acc)[4],
    unsigned short (*A_lds)[128][64], unsigned short (*B_lds)[128][64])
{
    const int tid  = threadIdx.x;
    const int lane = tid & 63;
    const int w    = tid >> 6;
    const int wm   = (w >> 1) << 6;
    const int wn   = (w & 1) << 6;
    const int qcol = lane & 15;
    const int quad = lane >> 4;

    const int srow = tid >> 3;   // 0..31
    const int sp   = tid & 7;

    auto stage = [&](int bf, int k0) {
#pragma unroll
        for (int i = 0; i < 4; ++i) {
            const int row  = (i << 5) + srow;            // 0..127
            const int gcol = ((sp ^ (row & 7)) << 3);
            async16(A + (size_t)(m0 + row) * EMB + k0 + gcol, &A_lds[bf][row][sp << 3]);
            async16(Bt + (size_t)row * EMB + k0 + gcol, &B_lds[bf][row][sp << 3]);
        }
    };

    stage(0, 0);
    stage(1, 64);            // prologue: 16 outstanding

    int c0 = 0, c1 = 1, c2 = 2;
    for (int ks = 0; ks < 8; ++ks) {
        if (ks < 6) {
            stage(c2, (ks + 2) << 6);                         // 24 outstanding
            asm volatile("s_waitcnt vmcnt(16)" ::: "memory");
        } else if (ks == 6) {
            asm volatile("s_waitcnt vmcnt(8)" ::: "memory");
        } else {
            asm volatile("s_waitcnt vmcnt(0)" ::: "memory");
        }
        __builtin_amdgcn_sched_barrier(0);
        __builtin_amdgcn_s_barrier();

#pragma unroll
        for (int kh = 0; kh < 2; ++kh) {
            bf16x8 af[4], bf[4];
#pragma unroll
            for (int i = 0; i < 4; ++i) {
                const int arow = wm + (i << 4) + qcol;
                af[i] = ldfrag(&A_lds[c0][arow][((((kh << 2) + quad) ^ (arow & 7)) << 3)]);
                const int brow = wn + (i << 4) + qcol;
                bf[i] = ldfrag(&B_lds[c0][brow][((((kh << 2) + quad) ^ (brow & 7)) << 3)]);
            }
#pragma unroll
            for (int i = 0; i < 4; ++i)
#pragma unroll
                for (int j = 0; j < 4; ++j) {
                    if (SWAP)
                        acc[i][j] = __builtin_amdgcn_mfma_f32_16x16x32_bf16(bf[j], af[i], acc[i][j], 0, 0, 0);
                    else
                        acc[i][j] = __builtin_amdgcn_mfma_f32_16x16x32_bf16(af[i], bf[j], acc[i][j], 0, 0, 0);
                }
        }
        __builtin_amdgcn_s_barrier();
        const int t = c0; c0 = c1; c1 = c2; c2 = t;
    }
}

// fused QKV: 768 blocks; XCD-grouped
__global__ __launch_bounds__(256) void gemm_qkv(
    const void* __restrict__ xq, const void* __restrict__ xkv,
    const unsigned short* __restrict__ Xc, const unsigned short* __restrict__ Wt,
    unsigned short* __restrict__ Qb, unsigned short* __restrict__ Kb,
    unsigned short* __restrict__ Vtb)
{
    const int flag = detect_flag((const unsigned short*)xq);
    __shared__ __align__(16) unsigned short A_lds[3][128][64];
    __shared__ __align__(16) unsigned short B_lds[3][128][64];
    const int blk = blockIdx.x;
    const int xcd = blk & 7, idx = blk >> 3;
    const int mi = idx / 12, ni = idx - mi * 12;
    const int m0 = ((xcd << 3) + mi) << 7;
    const int n0 = ni << 7;

    const unsigned short* A;
    if (flag) A = Xc + (n0 < 512 ? (size_t)0 : (size_t)M_ROWS * EMB);
    else      A = (const unsigned short*)(n0 < 512 ? xq : xkv);
    const unsigned short* Bt = Wt + (size_t)n0 * EMB;

    f32x4 acc[4][4];
#pragma unroll
    for (int i = 0; i < 4; ++i)
#pragma unroll
        for (int j = 0; j < 4; ++j) acc[i][j] = (f32x4){0.f, 0.f, 0.f, 0.f};

    const int lane = threadIdx.x & 63, w = threadIdx.x >> 6;
    const int wm = (w >> 1) << 6, wn = (w & 1) << 6;
    const int qcol = lane & 15, quad = lane >> 4;
    const int mode = n0 >> 9;   // 0=Q, 1=K, 2=V

    if (mode == 2) {
        mgemm_core7<false>(A, Bt, m0, acc, A_lds, B_lds);
#pragma unroll
        for (int ms = 0; ms < 4; ++ms)
#pragma unroll
            for (int ns = 0; ns < 4; ++ns) {
                const int mbase = m0 + wm + (ms << 4) + (quad << 2);
                const int n = n0 + wn + (ns << 4) + qcol;
                const int hd = n - 1024;
                const int hh = hd >> 6, d = hd & 63;
                const int bb = mbase >> 12, s = mbase & (S_LEN - 1);
                uint2 pk;
                pk.x = (unsigned int)f2b(acc[ms][ns][0]) | ((unsigned int)f2b(acc[ms][ns][1]) << 16);
                pk.y = (unsigned int)f2b(acc[ms][ns][2]) | ((unsigned int)f2b(acc[ms][ns][3]) << 16);
                *(uint2*)(Vtb + ((size_t)((bb * NH + hh) * DH + d)) * S_LEN + s) = pk;
            }
    } else {
        mgemm_core7<true>(A, Bt, m0, acc, A_lds, B_lds);
#pragma unroll
        for (int i = 0; i < 4; ++i)
#pragma unroll
            for (int j = 0; j < 4; ++j) {
                const int m  = m0 + wm + (i << 4) + qcol;
                const int nb = n0 + wn + (j << 4) + (quad << 2);
                uint2 pk;
                pk.x = (unsigned int)f2b(acc[i][j][0]) | ((unsigned int)f2b(acc[i][j][1]) << 16);
                pk.y = (unsigned int)f2b(acc[i][j][2]) | ((unsigned int)f2b(acc[i][j][3]) << 16);
                if (mode == 0) *(uint2*)(Qb + (size_t)m * HDIM + nb) = pk;
                else           *(uint2*)(Kb + (size_t)m * HDIM + (nb - 512)) = pk;
            }
    }
}

// output projection: 256 blocks; XCD-grouped
__global__ __launch_bounds__(256) void gemm_out(
    const void* __restrict__ xq,
    const unsigned short* __restrict__ A, const unsigned short* __restrict__ Bt,
    void* __restrict__ C)
{
    const int flag = detect_flag((const unsigned short*)xq);
    __shared__ __align__(16) unsigned short A_lds[3][128][64];
    __shared__ __align__(16) unsigned short B_lds[3][128][64];
    const int blk = blockIdx.x;
    const int xcd = blk & 7, idx = blk >> 3;
    const int mi = idx >> 2, ni = idx & 3;
    const int m0 = ((xcd << 3) + mi) << 7;
    const int n0 = ni << 7;

    f32x4 acc[4][4];
#pragma unroll
    for (int i = 0; i < 4; ++i)
#pragma unroll
        for (int j = 0; j < 4; ++j) acc[i][j] = (f32x4){0.f, 0.f, 0.f, 0.f};

    mgemm_core7<true>(A, Bt + (size_t)n0 * EMB, m0, acc, A_lds, B_lds);

    const int lane = threadIdx.x & 63, w = threadIdx.x >> 6;
    const int wm = (w >> 1) << 6, wn = (w & 1) << 6;
    const int qcol = lane & 15, quad = lane >> 4;
#pragma unroll
    for (int i = 0; i < 4; ++i)
#pragma unroll
        for (int j = 0; j < 4; ++j) {
            const int m  = m0 + wm + (i << 4) + qcol;
            const int nb = n0 + wn + (j << 4) + (quad << 2);
            if (flag) {
                float4 v = {acc[i][j][0], acc[i][j][1], acc[i][j][2], acc[i][j][3]};
                *(float4*)((float*)C + (size_t)m * HDIM + nb) = v;
            } else {
                uint2 pk;
                pk.x = (unsigned int)f2b(acc[i][j][0]) | ((unsigned int)f2b(acc[i][j][1]) << 16);
                pk.y = (unsigned int)f2b(acc[i][j][2]) | ((unsigned int)f2b(acc[i][j][3]) << 16);
                *(uint2*)((unsigned short*)C + (size_t)m * HDIM + nb) = pk;
            }
        }
}

// ---------- MFMA flash attention v7: 8-wave v6 + wave-uniform window specialization ----------
// R10 pre-fix: VALUBusy 38.6% vs MfmaUtil 7.6% at 19.7% occupancy. R13's 2x occupancy
// puts VALU at ~70-77% -> NOW VALU-bound (rule #23: R8's null was measured in the
// latency-bound regime). Re-apply the R8-refcheck-verified 3-way classification,
// re-derived for 16-query waves: dd in [diff-15, diff+15];
//   full-out:  |diff|>271 or seq-out -> zero P, skip MFMA+exp
//   full-in:   |diff|<=241 and seq-in -> exp-only path (no per-elem bounds)
//   partial:   original path
// + chunk-level wact gate. All branches wave-uniform; staging/vmcnt/barriers
// unconditional (sync structure identical to measured v6).
__global__ __launch_bounds__(512) void attn_mfma(
    const unsigned short* __restrict__ Q,
    const unsigned short* __restrict__ Kg,
    const unsigned short* __restrict__ Vt,
    unsigned short* __restrict__ O)
{
    __shared__ __align__(16) unsigned short K_lds[2][64][64];    // [buf][key][d]
    __shared__ __align__(16) unsigned short V_lds[2][64][64];    // [buf][d][key]
    __shared__ __align__(16) unsigned short P_lds[8][16][72];    // per-wave [q][key]

    const int tid  = threadIdx.x;
    const int lane = tid & 63;
    const int w    = tid >> 6;                      // 0..7
    const int blk  = blockIdx.x;
    const int bh   = blk >> 5;
    const int r5   = blk & 31;
    const int tile = ((r5 & 7) << 2) | (r5 >> 3);   // xcd = blk%8 owns 4 contiguous tiles
    const int h    = bh & (NH - 1);
    const int b    = bh >> 3;
    const int t0   = tile << 7;
    const int tq0  = t0 + (w << 4);                 // wave's 16 queries

    const int qcol = lane & 15;
    const int quad = lane >> 4;
    const float slope = 1.0f / (float)(2 << h);     // 2^-(h+1)

    const unsigned short* qrow =
        Q + (size_t)(b * S_LEN + tq0 + qcol) * HDIM + h * DH;
    const bf16x8 qf0 = ldfrag(qrow + quad * 8);
    const bf16x8 qf1 = ldfrag(qrow + 32 + quad * 8);

    f32x4 Oacc[4];
#pragma unroll
    for (int i = 0; i < 4; ++i) Oacc[i] = (f32x4){0.f, 0.f, 0.f, 0.f};
    float lsum = 0.f;

    const int srow = tid >> 3;   // 0..63
    const int sp   = tid & 7;

    // stage one 64-key chunk (2 global_load_lds per thread: 1 K-row seg + 1 V-row seg)
    auto stage = [&](int bf, int c) {
        const int j0 = t0 - HALF_W + (c << 6);
        const int gseg = (sp ^ (srow & 7)) << 3;
        const int jc = min(max(j0 + srow, 0), S_LEN - 1);
        async16(Kg + (size_t)(b * S_LEN + jc) * HDIM + h * DH + gseg,
                &K_lds[bf][srow][sp << 3]);
        const int js = min(max(j0 + gseg, 0), S_LEN - 8);
        async16(Vt + ((size_t)((b * NH + h) * DH + srow)) * S_LEN + js,
                &V_lds[bf][srow][sp << 3]);
    };

    stage(0, 0);   // prologue

    for (int c = 0; c < 10; ++c) {
        const int cur = c & 1;
        if (c < 9) {
            stage(cur ^ 1, c + 1);                       // prefetch next chunk
            asm volatile("s_waitcnt vmcnt(2)" ::: "memory");  // chunk c's 2 loads done
        } else {
            asm volatile("s_waitcnt vmcnt(0)" ::: "memory");
        }
        __builtin_amdgcn_sched_barrier(0);
        __builtin_amdgcn_s_barrier();                    // chunk c LDS visible to all waves

        const int j0 = t0 - HALF_W + (c << 6);

        // wave-level: does this chunk intersect this wave's window & the sequence?
        const bool wact = (j0 <= tq0 + 15 + HALF_W) && (j0 + 63 >= tq0 - HALF_W)
                       && (j0 < S_LEN) && (j0 + 63 >= 0);
        if (wact) {
        // S^T + mask/exp -> P_lds (3-way wave-uniform subtile classification)
#pragma unroll
        for (int ks = 0; ks < 4; ++ks) {
            const int J0   = j0 + (ks << 4);
            const int diff = tq0 - J0;               // wave-uniform
            unsigned short* pdst = &P_lds[w][qcol][(ks << 4) + (quad << 2)];
            if (diff > HALF_W + 15 || diff < -(HALF_W + 15) || J0 >= S_LEN || J0 + 15 < 0) {
                *(uint2*)pdst = (uint2){0u, 0u};     // fully masked: no MFMA, no exp
                continue;
            }
            const int krow = (ks << 4) + qcol;
            const bf16x8 kf0 = ldfrag(&K_lds[cur][krow][(quad ^ (krow & 7)) << 3]);
            const bf16x8 kf1 = ldfrag(&K_lds[cur][krow][((4 + quad) ^ (krow & 7)) << 3]);
            f32x4 z = (f32x4){0.f, 0.f, 0.f, 0.f};
            __builtin_amdgcn_s_setprio(1);
            z = __builtin_amdgcn_mfma_f32_16x16x32_bf16(kf0, qf0, z, 0, 0, 0);
            z = __builtin_amdgcn_mfma_f32_16x16x32_bf16(kf1, qf1, z, 0, 0, 0);
            __builtin_amdgcn_s_setprio(0);
            unsigned short pb[4];
            const float Df = (float)(diff + qcol - (quad << 2));  // dd = Df - r
            if (diff <= HALF_W - 15 && diff >= -(HALF_W - 15) && J0 >= 0 && J0 + 15 < S_LEN) {
                // fully inside window & sequence: exp-only fast path
#pragma unroll
                for (int r = 0; r < 4; ++r) {
                    const float s = z[r] * 0.125f - slope * fabsf(Df - (float)r);
                    const float p = __expf(s - 12.0f);
                    lsum += p;
                    pb[r] = f2b(p);
                }
            } else {
                // partial: per-element mask (original path)
#pragma unroll
                for (int r = 0; r < 4; ++r) {
                    const int j  = J0 + (quad << 2) + r;
                    const int dd = (tq0 + qcol) - j;
                    const bool ok = (j >= 0) && (j < S_LEN) && (dd <= HALF_W) && (dd >= -HALF_W);
                    const float s = z[r] * 0.125f - slope * fabsf((float)dd);
                    const float p = ok ? __expf(s - 12.0f) : 0.0f;
                    lsum += p;
                    pb[r] = f2b(p);
                }
            }
            uint2 pk;
            pk.x = (unsigned int)pb[0] | ((unsigned int)pb[1] << 16);
            pk.y = (unsigned int)pb[2] | ((unsigned int)pb[3] << 16);
            *(uint2*)pdst = pk;
        }
        // O^T += V^T P^T
        {
            const bf16x8 pf0 = ldfrag(&P_lds[w][qcol][quad * 8]);
            const bf16x8 pf1 = ldfrag(&P_lds[w][qcol][32 + quad * 8]);
#pragma unroll
            for (int ds = 0; ds < 4; ++ds) {
                const int vrow = (ds << 4) + qcol;
                const bf16x8 vf0 = ldfrag(&V_lds[cur][vrow][(quad ^ (vrow & 7)) << 3]);
                const bf16x8 vf1 = ldfrag(&V_lds[cur][vrow][((4 + quad) ^ (vrow & 7)) << 3]);
                __builtin_amdgcn_s_setprio(1);
                Oacc[ds] = __builtin_amdgcn_mfma_f32_16x16x32_bf16(vf0, pf0, Oacc[ds], 0, 0, 0);
                Oacc[ds] = __builtin_amdgcn_mfma_f32_16x16x32_bf16(vf1, pf1, Oacc[ds], 0, 0, 0);
                __builtin_amdgcn_s_setprio(0);
            }
        }
        }  // wact
        __builtin_amdgcn_s_barrier();   // all waves done reading buf[cur] before re-stage
    }

    {
        float l = lsum;
        l += __shfl_xor(l, 16, 64);
        l += __shfl_xor(l, 32, 64);
        const float rz = 1.0f / l;
        unsigned short* obase =
            O + (size_t)(b * S_LEN + tq0 + qcol) * HDIM + h * DH;
#pragma unroll
        for (int ds = 0; ds < 4; ++ds) {
            uint2 pk;
            pk.x = (unsigned int)f2b(Oacc[ds][0] * rz) |
                   ((unsigned int)f2b(Oacc[ds][1] * rz) << 16);
            pk.y = (unsigned int)f2b(Oacc[ds][2] * rz) |
                   ((unsigned int)f2b(Oacc[ds][3] * rz) << 16);
            *(uint2*)(obase + (ds << 4) + (quad << 2)) = pk;
        }
    }
}

// ---------- launch: 4 kernels ----------
extern "C" void kernel_launch(void* const* d_in, const int* in_sizes, int n_in,
                              void* d_out, int out_size, void* d_ws, size_t ws_size,
                              hipStream_t stream) {
    const void* xq  = d_in[0];
    const void* xkv = d_in[1];
    const void* wq  = d_in[2];
    const void* wk  = d_in[3];
    const void* wv  = d_in[4];
    const void* wo  = d_in[5];

    // ws: [pad 256B][Q/A 8MB][K 8MB][Vt 8MB][Wt 4x0.5MB]; bf16 input staging in d_out
    unsigned short* Qb  = (unsigned short*)((char*)d_ws + 256);
    unsigned short* Kb  = Qb  + (size_t)M_ROWS * HDIM;
    unsigned short* Vtb = Kb  + (size_t)M_ROWS * HDIM;
    unsigned short* Wt  = Vtb + (size_t)M_ROWS * HDIM;
    unsigned short* Wto = Wt + (size_t)3 * EMB * EMB;
    unsigned short* Xc  = (unsigned short*)d_out;   // dead until gemm_out writes it

    prep<<<1024 + 4096, 256, 0, stream>>>(xq, xkv, wq, wk, wv, wo, Wt, Xc);
    gemm_qkv<<<768, 256, 0, stream>>>(xq, xkv, Xc, Wt, Qb, Kb, Vtb);
    attn_mfma<<<BATCH * NH * (S_LEN / 128), 512, 0, stream>>>(Qb, Kb, Vtb, Qb);
    gemm_out<<<256, 256, 0, stream>>>(xq, Qb, Wto, d_out);
}

// Round 18
// 149.172 us; speedup vs baseline: 1.0703x; 1.0319x over previous
//
#include <hip/hip_runtime.h>

// Problem: B=2, S=4096, E=512, H=8, D=64, window 512->513 (HALF=256)
#define S_LEN  4096
#define NH     8
#define DH     64
#define EMB    512
#define HDIM   512
#define HALF_W 256
#define BATCH  2
#define M_ROWS (BATCH * S_LEN)  // 8192

typedef __attribute__((ext_vector_type(8))) short bf16x8;
typedef __attribute__((ext_vector_type(4))) float f32x4;

// ---------- bf16 helpers ----------
__device__ __forceinline__ float b2f(unsigned short u) {
    union { unsigned int i; float f; } v; v.i = ((unsigned int)u) << 16; return v.f;
}
__device__ __forceinline__ unsigned short f2b(float f) {
    unsigned int x = __float_as_uint(f);
    unsigned int r = (x + 0x7fffu + ((x >> 16) & 1u)) >> 16;   // RNE
    return (unsigned short)r;
}
__device__ __forceinline__ void unpack2(unsigned int u, float* d) {
    d[0] = b2f((unsigned short)(u & 0xffffu));
    d[1] = b2f((unsigned short)(u >> 16));
}
union FragU { uint4 u; bf16x8 f; };
__device__ __forceinline__ bf16x8 ldfrag(const unsigned short* p) {
    FragU x; x.u = *(const uint4*)p; return x.f;
}

// ---------- async global->LDS, 16B per lane (m97 pattern) ----------
__device__ __forceinline__ void async16(const unsigned short* g, unsigned short* l) {
    __builtin_amdgcn_global_load_lds(
        (__attribute__((address_space(1))) void*)const_cast<unsigned short*>(g),
        (__attribute__((address_space(3))) void*)l, 16, 0, 0);
}

// ---------- inline dtype detect (per-block; deterministic, L2-hot scan) ----------
__device__ __forceinline__ int detect_flag(const unsigned short* __restrict__ xq) {
    __shared__ int s_flag;
    if (threadIdx.x == 0) s_flag = 0;
    __syncthreads();
    uint4 u = *(const uint4*)(xq + threadIdx.x * 8);
    const unsigned short* us = (const unsigned short*)&u;
    int bad = 0;
#pragma unroll
    for (int i = 0; i < 8; ++i) {
        float v = b2f(us[i]);
        if (!(fabsf(v) < 1.0e6f)) bad = 1;
    }
    if (__any(bad) && (threadIdx.x & 63) == 0) atomicOr(&s_flag, 1);
    __syncthreads();
    return s_flag;   // 1 = fp32 inputs, 0 = bf16 inputs
}

// ---------- fused prep: weight transpose->Wt[n][k] bf16  +  input fp32->bf16 convert ----------
__global__ __launch_bounds__(256) void prep(
    const void* __restrict__ xq, const void* __restrict__ xkv,
    const void* __restrict__ w0, const void* __restrict__ w1,
    const void* __restrict__ w2, const void* __restrict__ w3,
    unsigned short* __restrict__ Wt, unsigned short* __restrict__ Xc)
{
    const int flag = detect_flag((const unsigned short*)xq);
    const int blk = blockIdx.x;
    if (blk < 1024) {
        __shared__ float t[32][33];
        const int z = blk >> 8, idx = blk & 255;
        const void* src = (z == 0) ? w0 : (z == 1) ? w1 : (z == 2) ? w2 : w3;
        unsigned short* dst = Wt + (size_t)z * EMB * EMB;
        const int n0 = (idx & 15) << 5, k0 = (idx >> 4) << 5;
        const int kk = threadIdx.x >> 3;
        const int n4 = (threadIdx.x & 7) << 2;
        if (flag) {
            float4 v = *(const float4*)((const float*)src + (size_t)(k0 + kk) * EMB + n0 + n4);
            t[kk][n4] = v.x; t[kk][n4 + 1] = v.y; t[kk][n4 + 2] = v.z; t[kk][n4 + 3] = v.w;
        } else {
            uint2 u = *(const uint2*)((const unsigned short*)src + (size_t)(k0 + kk) * EMB + n0 + n4);
            unpack2(u.x, &t[kk][n4]); unpack2(u.y, &t[kk][n4 + 2]);
        }
        __syncthreads();
        const int nn = threadIdx.x >> 3;
        const int ks = (threadIdx.x & 7) << 2;
        uint2 pk;
        pk.x = (unsigned int)f2b(t[ks + 0][nn]) | ((unsigned int)f2b(t[ks + 1][nn]) << 16);
        pk.y = (unsigned int)f2b(t[ks + 2][nn]) | ((unsigned int)f2b(t[ks + 3][nn]) << 16);
        *(uint2*)(dst + (size_t)(n0 + nn) * EMB + k0 + ks) = pk;
    } else {
        if (!flag) return;
        const int idx = blk - 1024;
        const int z = idx >> 11;                 // 0 = xq, 1 = xkv
        const float* src = (const float*)(z ? xkv : xq);
        unsigned short* dst = Xc + (size_t)z * M_ROWS * EMB;
        const size_t base = ((size_t)(idx & 2047) * 256 + threadIdx.x) * 8;
        float4 a = *(const float4*)(src + base);
        float4 b = *(const float4*)(src + base + 4);
        uint4 pk;
        pk.x = (unsigned int)f2b(a.x) | ((unsigned int)f2b(a.y) << 16);
        pk.y = (unsigned int)f2b(a.z) | ((unsigned int)f2b(a.w) << 16);
        pk.z = (unsigned int)f2b(b.x) | ((unsigned int)f2b(b.y) << 16);
        pk.w = (unsigned int)f2b(b.z) | ((unsigned int)f2b(b.w) << 16);
        *(uint4*)(dst + base) = pk;
    }
}

// ---------- MFMA GEMM core v9: 512 threads / 8 waves, wave-tile 64x32, dbuf BK=64 ----------
// R13's occupancy lesson applied to GEMM: v7 ran 4 waves/block @ 96 KB LDS -> 1 blk/CU
// -> 1 wave/SIMD; every vmcnt+barrier left SIMDs empty (why R9 deepening & R14
// barrier-halving were both neutral). v9: 8 waves (2m x 4n wave grid, 64x32/wave),
// dbuf 64 KB -> 2 blocks/CU -> 16 waves/CU (4x TLP). Staging: srow=tid>>3 (0..63),
// i in {0,1} -> 128 rows x 8 segs = 1024 slots = 512 thr x 2; 4 loads/thread/step
// -> counted vmcnt(4) (exact; no other in-loop VMEM); v6 2-barrier WAR proof.
template<bool SWAP>
__device__ __forceinline__ void mgemm_core9(
    const unsigned short* __restrict__ A, const unsigned short* __restrict__ Bt,
    int m0, f32x4 (*acc)[2],
    unsigned short (*A_lds)[128][64], unsigned short (*B_lds)[128][64])
{
    const int tid  = threadIdx.x;
    const int lane = tid & 63;
    const int w    = tid >> 6;           // 0..7
    const int wm   = (w >> 2) << 6;      // 0, 64
    const int wn   = (w & 3) << 5;       // 0, 32, 64, 96
    const int qcol = lane & 15;
    const int quad = lane >> 4;

    const int srow = tid >> 3;   // 0..63
    const int sp   = tid & 7;

    auto stage = [&](int bf, int k0) {
#pragma unroll
        for (int i = 0; i < 2; ++i) {
            const int row  = (i << 6) + srow;            // 0..127
            const int gcol = ((sp ^ (row & 7)) << 3);
            async16(A + (size_t)(m0 + row) * EMB + k0 + gcol, &A_lds[bf][row][sp << 3]);
            async16(Bt + (size_t)row * EMB + k0 + gcol, &B_lds[bf][row][sp << 3]);
        }
    };

    stage(0, 0);   // prologue: 4 outstanding

    for (int ks = 0; ks < 8; ++ks) {
        const int cur = ks & 1;
        if (ks < 7) {
            stage(cur ^ 1, (ks + 1) << 6);                // 8 outstanding
            asm volatile("s_waitcnt vmcnt(4)" ::: "memory");  // step-ks loads landed
        } else {
            asm volatile("s_waitcnt vmcnt(0)" ::: "memory");
        }
        __builtin_amdgcn_sched_barrier(0);
        __builtin_amdgcn_s_barrier();

#pragma unroll
        for (int kh = 0; kh < 2; ++kh) {
            bf16x8 af[4], bf[2];
#pragma unroll
            for (int i = 0; i < 4; ++i) {
                const int arow = wm + (i << 4) + qcol;
                af[i] = ldfrag(&A_lds[cur][arow][((((kh << 2) + quad) ^ (arow & 7)) << 3)]);
            }
#pragma unroll
            for (int j = 0; j < 2; ++j) {
                const int brow = wn + (j << 4) + qcol;
                bf[j] = ldfrag(&B_lds[cur][brow][((((kh << 2) + quad) ^ (brow & 7)) << 3)]);
            }
#pragma unroll
            for (int i = 0; i < 4; ++i)
#pragma unroll
                for (int j = 0; j < 2; ++j) {
                    if (SWAP)
                        acc[i][j] = __builtin_amdgcn_mfma_f32_16x16x32_bf16(bf[j], af[i], acc[i][j], 0, 0, 0);
                    else
                        acc[i][j] = __builtin_amdgcn_mfma_f32_16x16x32_bf16(af[i], bf[j], acc[i][j], 0, 0, 0);
                }
        }
        __builtin_amdgcn_s_barrier();   // all waves done reading buf[cur] before re-stage
    }
}

// fused QKV: 768 blocks x 512 threads; XCD-grouped
__global__ __launch_bounds__(512) void gemm_qkv(
    const void* __restrict__ xq, const void* __restrict__ xkv,
    const unsigned short* __restrict__ Xc, const unsigned short* __restrict__ Wt,
    unsigned short* __restrict__ Qb, unsigned short* __restrict__ Kb,
    unsigned short* __restrict__ Vtb)
{
    const int flag = detect_flag((const unsigned short*)xq);
    __shared__ __align__(16) unsigned short A_lds[2][128][64];
    __shared__ __align__(16) unsigned short B_lds[2][128][64];
    const int blk = blockIdx.x;
    const int xcd = blk & 7, idx = blk >> 3;
    const int mi = idx / 12, ni = idx - mi * 12;
    const int m0 = ((xcd << 3) + mi) << 7;
    const int n0 = ni << 7;

    const unsigned short* A;
    if (flag) A = Xc + (n0 < 512 ? (size_t)0 : (size_t)M_ROWS * EMB);
    else      A = (const unsigned short*)(n0 < 512 ? xq : xkv);
    const unsigned short* Bt = Wt + (size_t)n0 * EMB;

    f32x4 acc[4][2];
#pragma unroll
    for (int i = 0; i < 4; ++i)
#pragma unroll
        for (int j = 0; j < 2; ++j) acc[i][j] = (f32x4){0.f, 0.f, 0.f, 0.f};

    const int lane = threadIdx.x & 63, w = threadIdx.x >> 6;
    const int wm = (w >> 2) << 6, wn = (w & 3) << 5;
    const int qcol = lane & 15, quad = lane >> 4;
    const int mode = n0 >> 9;   // 0=Q, 1=K, 2=V (512%128==0: tile stays in one mode)

    if (mode == 2) {
        // V: non-swapped core; pack along r -> m=s consecutive (verified R9)
        mgemm_core9<false>(A, Bt, m0, acc, A_lds, B_lds);
#pragma unroll
        for (int ms = 0; ms < 4; ++ms)
#pragma unroll
            for (int ns = 0; ns < 2; ++ns) {
                const int mbase = m0 + wm + (ms << 4) + (quad << 2);
                const int n = n0 + wn + (ns << 4) + qcol;
                const int hd = n - 1024;
                const int hh = hd >> 6, d = hd & 63;
                const int bb = mbase >> 12, s = mbase & (S_LEN - 1);
                uint2 pk;
                pk.x = (unsigned int)f2b(acc[ms][ns][0]) | ((unsigned int)f2b(acc[ms][ns][1]) << 16);
                pk.y = (unsigned int)f2b(acc[ms][ns][2]) | ((unsigned int)f2b(acc[ms][ns][3]) << 16);
                *(uint2*)(Vtb + ((size_t)((bb * NH + hh) * DH + d)) * S_LEN + s) = pk;
            }
    } else {
        // Q/K: swapped core; lane holds 4 consecutive n -> one 8B store per subtile
        mgemm_core9<true>(A, Bt, m0, acc, A_lds, B_lds);
#pragma unroll
        for (int i = 0; i < 4; ++i)
#pragma unroll
            for (int j = 0; j < 2; ++j) {
                const int m  = m0 + wm + (i << 4) + qcol;
                const int nb = n0 + wn + (j << 4) + (quad << 2);
                uint2 pk;
                pk.x = (unsigned int)f2b(acc[i][j][0]) | ((unsigned int)f2b(acc[i][j][1]) << 16);
                pk.y = (unsigned int)f2b(acc[i][j][2]) | ((unsigned int)f2b(acc[i][j][3]) << 16);
                if (mode == 0) *(uint2*)(Qb + (size_t)m * HDIM + nb) = pk;
                else           *(uint2*)(Kb + (size_t)m * HDIM + (nb - 512)) = pk;
            }
    }
}

// output projection: 256 blocks x 512 threads; XCD-grouped; swapped core
__global__ __launch_bounds__(512) void gemm_out(
    const void* __restrict__ xq,
    const unsigned short* __restrict__ A, const unsigned short* __restrict__ Bt,
    void* __restrict__ C)
{
    const int flag = detect_flag((const unsigned short*)xq);
    __shared__ __align__(16) unsigned short A_lds[2][128][64];
    __shared__ __align__(16) unsigned short B_lds[2][128][64];
    const int blk = blockIdx.x;
    const int xcd = blk & 7, idx = blk >> 3;
    const int mi = idx >> 2, ni = idx & 3;
    const int m0 = ((xcd << 3) + mi) << 7;
    const int n0 = ni << 7;

    f32x4 acc[4][2];
#pragma unroll
    for (int i = 0; i < 4; ++i)
#pragma unroll
        for (int j = 0; j < 2; ++j) acc[i][j] = (f32x4){0.f, 0.f, 0.f, 0.f};

    mgemm_core9<true>(A, Bt + (size_t)n0 * EMB, m0, acc, A_lds, B_lds);

    const int lane = threadIdx.x & 63, w = threadIdx.x >> 6;
    const int wm = (w >> 2) << 6, wn = (w & 3) << 5;
    const int qcol = lane & 15, quad = lane >> 4;
#pragma unroll
    for (int i = 0; i < 4; ++i)
#pragma unroll
        for (int j = 0; j < 2; ++j) {
            const int m  = m0 + wm + (i << 4) + qcol;
            const int nb = n0 + wn + (j << 4) + (quad << 2);
            if (flag) {
                float4 v = {acc[i][j][0], acc[i][j][1], acc[i][j][2], acc[i][j][3]};
                *(float4*)((float*)C + (size_t)m * HDIM + nb) = v;
            } else {
                uint2 pk;
                pk.x = (unsigned int)f2b(acc[i][j][0]) | ((unsigned int)f2b(acc[i][j][1]) << 16);
                pk.y = (unsigned int)f2b(acc[i][j][2]) | ((unsigned int)f2b(acc[i][j][3]) << 16);
                *(uint2*)((unsigned short*)C + (size_t)m * HDIM + nb) = pk;
            }
        }
}

// ---------- MFMA flash attention v7 (unchanged; part of measured 153.92 config) ----------
__global__ __launch_bounds__(512) void attn_mfma(
    const unsigned short* __restrict__ Q,
    const unsigned short* __restrict__ Kg,
    const unsigned short* __restrict__ Vt,
    unsigned short* __restrict__ O)
{
    __shared__ __align__(16) unsigned short K_lds[2][64][64];    // [buf][key][d]
    __shared__ __align__(16) unsigned short V_lds[2][64][64];    // [buf][d][key]
    __shared__ __align__(16) unsigned short P_lds[8][16][72];    // per-wave [q][key]

    const int tid  = threadIdx.x;
    const int lane = tid & 63;
    const int w    = tid >> 6;                      // 0..7
    const int blk  = blockIdx.x;
    const int bh   = blk >> 5;
    const int r5   = blk & 31;
    const int tile = ((r5 & 7) << 2) | (r5 >> 3);   // xcd = blk%8 owns 4 contiguous tiles
    const int h    = bh & (NH - 1);
    const int b    = bh >> 3;
    const int t0   = tile << 7;
    const int tq0  = t0 + (w << 4);                 // wave's 16 queries

    const int qcol = lane & 15;
    const int quad = lane >> 4;
    const float slope = 1.0f / (float)(2 << h);     // 2^-(h+1)

    const unsigned short* qrow =
        Q + (size_t)(b * S_LEN + tq0 + qcol) * HDIM + h * DH;
    const bf16x8 qf0 = ldfrag(qrow + quad * 8);
    const bf16x8 qf1 = ldfrag(qrow + 32 + quad * 8);

    f32x4 Oacc[4];
#pragma unroll
    for (int i = 0; i < 4; ++i) Oacc[i] = (f32x4){0.f, 0.f, 0.f, 0.f};
    float lsum = 0.f;

    const int srow = tid >> 3;   // 0..63
    const int sp   = tid & 7;

    // stage one 64-key chunk (2 global_load_lds per thread: 1 K-row seg + 1 V-row seg)
    auto stage = [&](int bf, int c) {
        const int j0 = t0 - HALF_W + (c << 6);
        const int gseg = (sp ^ (srow & 7)) << 3;
        const int jc = min(max(j0 + srow, 0), S_LEN - 1);
        async16(Kg + (size_t)(b * S_LEN + jc) * HDIM + h * DH + gseg,
                &K_lds[bf][srow][sp << 3]);
        const int js = min(max(j0 + gseg, 0), S_LEN - 8);
        async16(Vt + ((size_t)((b * NH + h) * DH + srow)) * S_LEN + js,
                &V_lds[bf][srow][sp << 3]);
    };

    stage(0, 0);   // prologue

    for (int c = 0; c < 10; ++c) {
        const int cur = c & 1;
        if (c < 9) {
            stage(cur ^ 1, c + 1);                       // prefetch next chunk
            asm volatile("s_waitcnt vmcnt(2)" ::: "memory");  // chunk c's 2 loads done
        } else {
            asm volatile("s_waitcnt vmcnt(0)" ::: "memory");
        }
        __builtin_amdgcn_sched_barrier(0);
        __builtin_amdgcn_s_barrier();                    // chunk c LDS visible to all waves

        const int j0 = t0 - HALF_W + (c << 6);

        // wave-level: does this chunk intersect this wave's window & the sequence?
        const bool wact = (j0 <= tq0 + 15 + HALF_W) && (j0 + 63 >= tq0 - HALF_W)
                       && (j0 < S_LEN) && (j0 + 63 >= 0);
        if (wact) {
        // S^T + mask/exp -> P_lds (3-way wave-uniform subtile classification)
#pragma unroll
        for (int ks = 0; ks < 4; ++ks) {
            const int J0   = j0 + (ks << 4);
            const int diff = tq0 - J0;               // wave-uniform
            unsigned short* pdst = &P_lds[w][qcol][(ks << 4) + (quad << 2)];
            if (diff > HALF_W + 15 || diff < -(HALF_W + 15) || J0 >= S_LEN || J0 + 15 < 0) {
                *(uint2*)pdst = (uint2){0u, 0u};     // fully masked: no MFMA, no exp
                continue;
            }
            const int krow = (ks << 4) + qcol;
            const bf16x8 kf0 = ldfrag(&K_lds[cur][krow][(quad ^ (krow & 7)) << 3]);
            const bf16x8 kf1 = ldfrag(&K_lds[cur][krow][((4 + quad) ^ (krow & 7)) << 3]);
            f32x4 z = (f32x4){0.f, 0.f, 0.f, 0.f};
            __builtin_amdgcn_s_setprio(1);
            z = __builtin_amdgcn_mfma_f32_16x16x32_bf16(kf0, qf0, z, 0, 0, 0);
            z = __builtin_amdgcn_mfma_f32_16x16x32_bf16(kf1, qf1, z, 0, 0, 0);
            __builtin_amdgcn_s_setprio(0);
            unsigned short pb[4];
            const float Df = (float)(diff + qcol - (quad << 2));  // dd = Df - r
            if (diff <= HALF_W - 15 && diff >= -(HALF_W - 15) && J0 >= 0 && J0 + 15 < S_LEN) {
                // fully inside window & sequence: exp-only fast path
#pragma unroll
                for (int r = 0; r < 4; ++r) {
                    const float s = z[r] * 0.125f - slope * fabsf(Df - (float)r);
                    const float p = __expf(s - 12.0f);
                    lsum += p;
                    pb[r] = f2b(p);
                }
            } else {
                // partial: per-element mask (original path)
#pragma unroll
                for (int r = 0; r < 4; ++r) {
                    const int j  = J0 + (quad << 2) + r;
                    const int dd = (tq0 + qcol) - j;
                    const bool ok = (j >= 0) && (j < S_LEN) && (dd <= HALF_W) && (dd >= -HALF_W);
                    const float s = z[r] * 0.125f - slope * fabsf((float)dd);
                    const float p = ok ? __expf(s - 12.0f) : 0.0f;
                    lsum += p;
                    pb[r] = f2b(p);
                }
            }
            uint2 pk;
            pk.x = (unsigned int)pb[0] | ((unsigned int)pb[1] << 16);
            pk.y = (unsigned int)pb[2] | ((unsigned int)pb[3] << 16);
            *(uint2*)pdst = pk;
        }
        // O^T += V^T P^T
        {
            const bf16x8 pf0 = ldfrag(&P_lds[w][qcol][quad * 8]);
            const bf16x8 pf1 = ldfrag(&P_lds[w][qcol][32 + quad * 8]);
#pragma unroll
            for (int ds = 0; ds < 4; ++ds) {
                const int vrow = (ds << 4) + qcol;
                const bf16x8 vf0 = ldfrag(&V_lds[cur][vrow][(quad ^ (vrow & 7)) << 3]);
                const bf16x8 vf1 = ldfrag(&V_lds[cur][vrow][((4 + quad) ^ (vrow & 7)) << 3]);
                __builtin_amdgcn_s_setprio(1);
                Oacc[ds] = __builtin_amdgcn_mfma_f32_16x16x32_bf16(vf0, pf0, Oacc[ds], 0, 0, 0);
                Oacc[ds] = __builtin_amdgcn_mfma_f32_16x16x32_bf16(vf1, pf1, Oacc[ds], 0, 0, 0);
                __builtin_amdgcn_s_setprio(0);
            }
        }
        }  // wact
        __builtin_amdgcn_s_barrier();   // all waves done reading buf[cur] before re-stage
    }

    {
        float l = lsum;
        l += __shfl_xor(l, 16, 64);
        l += __shfl_xor(l, 32, 64);
        const float rz = 1.0f / l;
        unsigned short* obase =
            O + (size_t)(b * S_LEN + tq0 + qcol) * HDIM + h * DH;
#pragma unroll
        for (int ds = 0; ds < 4; ++ds) {
            uint2 pk;
            pk.x = (unsigned int)f2b(Oacc[ds][0] * rz) |
                   ((unsigned int)f2b(Oacc[ds][1] * rz) << 16);
            pk.y = (unsigned int)f2b(Oacc[ds][2] * rz) |
                   ((unsigned int)f2b(Oacc[ds][3] * rz) << 16);
            *(uint2*)(obase + (ds << 4) + (quad << 2)) = pk;
        }
    }
}

// ---------- launch: 4 kernels ----------
extern "C" void kernel_launch(void* const* d_in, const int* in_sizes, int n_in,
                              void* d_out, int out_size, void* d_ws, size_t ws_size,
                              hipStream_t stream) {
    const void* xq  = d_in[0];
    const void* xkv = d_in[1];
    const void* wq  = d_in[2];
    const void* wk  = d_in[3];
    const void* wv  = d_in[4];
    const void* wo  = d_in[5];

    // ws: [pad 256B][Q/A 8MB][K 8MB][Vt 8MB][Wt 4x0.5MB]; bf16 input staging in d_out
    unsigned short* Qb  = (unsigned short*)((char*)d_ws + 256);
    unsigned short* Kb  = Qb  + (size_t)M_ROWS * HDIM;
    unsigned short* Vtb = Kb  + (size_t)M_ROWS * HDIM;
    unsigned short* Wt  = Vtb + (size_t)M_ROWS * HDIM;
    unsigned short* Wto = Wt + (size_t)3 * EMB * EMB;
    unsigned short* Xc  = (unsigned short*)d_out;   // dead until gemm_out writes it

    prep<<<1024 + 4096, 256, 0, stream>>>(xq, xkv, wq, wk, wv, wo, Wt, Xc);
    gemm_qkv<<<768, 512, 0, stream>>>(xq, xkv, Xc, Wt, Qb, Kb, Vtb);
    attn_mfma<<<BATCH * NH * (S_LEN / 128), 512, 0, stream>>>(Qb, Kb, Vtb, Qb);
    gemm_out<<<256, 512, 0, stream>>>(xq, Qb, Wto, d_out);
}